// Round 6
// baseline (98289.948 us; speedup 1.0000x reference)
//
#include <hip/hip_runtime.h>
#include <math.h>

// ---------------------------------------------------------------------------
// Seq2Seq forward. V=50000 E=H=512 Lin=400 Tout=100 B=64 Lmax=400.
// R6: ONE persistent mega-kernel (256 blocks x 256 thr, 1 block/CU,
// co-resident) for encoder + decoder + loss. Atomic grid barriers:
//   ebar: 32-participant, 400 encoder steps (R5-proven mechanism)
//   gbar: 256-participant, 3 per decoder step + phase transitions
// Graph = 2 nodes (k_init + k_mega). Weight bf16 conversion in phase 0.
// ---------------------------------------------------------------------------

typedef __attribute__((ext_vector_type(8))) short bh8;   // 8 x bf16 = 4 VGPR
typedef __attribute__((ext_vector_type(4))) float fv4;

// round-to-nearest-even f32 -> bf16 bits
__device__ __forceinline__ short f2b(float f) {
    union { float f; unsigned int u; } c; c.f = f;
    unsigned int r = (c.u + 0x7fffu + ((c.u >> 16) & 1u)) >> 16;
    return (short)r;
}
__device__ __forceinline__ bh8 ld8(const float* __restrict__ p) {
    bh8 r;
    #pragma unroll
    for (int j = 0; j < 8; ++j) r[j] = f2b(p[j]);
    return r;
}
__device__ __forceinline__ float sigmf(float x) { return 1.f / (1.f + expf(-x)); }
__device__ __forceinline__ fv4 mfma16(bh8 a, bh8 b, fv4 c) {
    return __builtin_amdgcn_mfma_f32_16x16x32_bf16(a, b, c, 0, 0, 0);
}

// Grid barrier among participating blocks (monotone counter, agent scope).
// All participants co-resident; release add publishes prior stores, acquire
// spin invalidates caches. Proven in R5 encoder.
__device__ __forceinline__ void spinbar(unsigned int* bar, unsigned int target) {
    __syncthreads();
    if (threadIdx.x == 0) {
        __hip_atomic_fetch_add(bar, 1u, __ATOMIC_ACQ_REL, __HIP_MEMORY_SCOPE_AGENT);
        while (__hip_atomic_load(bar, __ATOMIC_ACQUIRE, __HIP_MEMORY_SCOPE_AGENT) < target)
            __builtin_amdgcn_s_sleep(8);
    }
    __syncthreads();
}
__device__ __forceinline__ void spinbar2(unsigned int* bar, unsigned int target) {
    __syncthreads();
    if (threadIdx.x == 0) {
        __hip_atomic_fetch_add(bar, 1u, __ATOMIC_ACQ_REL, __HIP_MEMORY_SCOPE_AGENT);
        while (__hip_atomic_load(bar, __ATOMIC_ACQUIRE, __HIP_MEMORY_SCOPE_AGENT) < target)
            __builtin_amdgcn_s_sleep(2);
    }
    __syncthreads();
}

__device__ __forceinline__ void cvtbuf(const float* __restrict__ s,
                                       short* __restrict__ d, int n, int gtid) {
    for (int i = gtid * 4; i < n; i += 65536 * 4) {
        fv4 v = *(const fv4*)(s + i);
        short4 o; o.x = f2b(v[0]); o.y = f2b(v[1]); o.z = f2b(v[2]); o.w = f2b(v[3]);
        *(short4*)(d + i) = o;
    }
}

__global__ void k_init(float* lacc, unsigned int* gbar, unsigned int* ebar) {
    *lacc = 0.f; *gbar = 0u; *ebar = 0u;
}

__global__ __launch_bounds__(256, 1) void k_mega(
    const float* __restrict__ emb,
    const float* __restrict__ encWih, const float* __restrict__ encWhh,
    const float* __restrict__ encbih, const float* __restrict__ encbhh,
    const float* __restrict__ attnW,  const float* __restrict__ attnb,
    const float* __restrict__ combW,  const float* __restrict__ combb,
    const float* __restrict__ decWih, const float* __restrict__ decWhh,
    const float* __restrict__ decbih, const float* __restrict__ decbhh,
    const float* __restrict__ outW,   const float* __restrict__ outb,
    const int* __restrict__ input_t,  const int* __restrict__ target_t,
    float* __restrict__ h_f32, short* __restrict__ h_bf,
    float* __restrict__ enc0, short* __restrict__ c_bf,
    float* __restrict__ pm, float* __restrict__ ps, float* __restrict__ tlog,
    float* __restrict__ lacc, unsigned int* __restrict__ gbar,
    unsigned int* __restrict__ ebar,
    short* __restrict__ encWb, short* __restrict__ decWb,
    short* __restrict__ outWb, int tier, float* __restrict__ outp)
{
    __shared__ float sx[1024];
    __shared__ float sc[400];
    __shared__ float red[256];
    __shared__ float rs2[256];
    __shared__ float a0s;
    __shared__ float sl[64][65];
    __shared__ float sqm[256];
    __shared__ float sqs[256];

    const int bid = blockIdx.x;
    const int tid = threadIdx.x;
    const int gtid = bid * 256 + tid;
    unsigned int gc = 0;

    // ================= phase 0: init h, convert weights ====================
    if (gtid < 32768) { h_f32[gtid] = 0.f; h_bf[gtid] = 0; }
    if (tier >= 1) {
        cvtbuf(encWih, encWb, 786432, gtid);
        cvtbuf(encWhh, encWb + 786432, 786432, gtid);
        cvtbuf(decWih, decWb, 786432, gtid);
        cvtbuf(decWhh, decWb + 786432, 786432, gtid);
    }
    if (tier >= 2) cvtbuf(outW, outWb, 25600000, gtid);
    gc += 256; spinbar(gbar, gc);

    // ================= encoder: 400 GRU steps, 32 blocks ===================
    if (bid < 32) {
        const int wv = tid >> 6, lane = tid & 63;
        const int l15 = lane & 15, ko = lane >> 4, koff = ko * 8;
        const int n0 = bid * 16, b0 = wv * 16;
        const int brow = b0 + l15, n = n0 + l15;
        const float bir = encbih[n], biz = encbih[n + 512], bin = encbih[n + 1024];
        const float bhr = encbhh[n], bhz = encbhh[n + 512], bhn = encbhh[n + 1024];
        unsigned int ec = 0;
        #pragma unroll 1
        for (int t = 0; t < 400; ++t) {
            const float* hi  = h_f32 + (t & 1) * 32768;
            const short* hib = h_bf  + (t & 1) * 32768;
            float* ho  = h_f32 + ((t + 1) & 1) * 32768;
            short* hob = h_bf  + ((t + 1) & 1) * 32768;
            const int tok = input_t[t * 64 + brow];
            const float* Ap = emb + (long long)tok * 512 + koff;
            const bh8*  Hp  = (const bh8*)(hib + (long long)brow * 512) + ko;
            fv4 air = {0.f, 0.f, 0.f, 0.f};
            fv4 aiz = air, ain = air, ahr = air, ahz = air, ahn = air;
            if (tier >= 1) {
                const bh8* Wr = (const bh8*)(encWb + (long long)(n + 0)    * 512) + ko;
                const bh8* Wz = (const bh8*)(encWb + (long long)(n + 512)  * 512) + ko;
                const bh8* Wn = (const bh8*)(encWb + (long long)(n + 1024) * 512) + ko;
                const bh8* Ur = (const bh8*)(encWb + (long long)(n + 1536) * 512) + ko;
                const bh8* Uz = (const bh8*)(encWb + (long long)(n + 2048) * 512) + ko;
                const bh8* Un = (const bh8*)(encWb + (long long)(n + 2560) * 512) + ko;
                #pragma unroll 4
                for (int kk = 0; kk < 16; ++kk) {
                    const bh8 a = ld8(Ap + kk * 32);
                    const bh8 h = Hp[kk * 4];
                    air = mfma16(a, Wr[kk * 4], air);
                    aiz = mfma16(a, Wz[kk * 4], aiz);
                    ain = mfma16(a, Wn[kk * 4], ain);
                    ahr = mfma16(h, Ur[kk * 4], ahr);
                    ahz = mfma16(h, Uz[kk * 4], ahz);
                    ahn = mfma16(h, Un[kk * 4], ahn);
                }
            } else {
                const float* Wr = encWih + (long long)(n + 0)    * 512 + koff;
                const float* Wz = encWih + (long long)(n + 512)  * 512 + koff;
                const float* Wn = encWih + (long long)(n + 1024) * 512 + koff;
                const float* Ur = encWhh + (long long)(n + 0)    * 512 + koff;
                const float* Uz = encWhh + (long long)(n + 512)  * 512 + koff;
                const float* Un = encWhh + (long long)(n + 1024) * 512 + koff;
                #pragma unroll 4
                for (int kk = 0; kk < 16; ++kk) {
                    const bh8 a = ld8(Ap + kk * 32);
                    const bh8 h = Hp[kk * 4];
                    air = mfma16(a, ld8(Wr + kk * 32), air);
                    aiz = mfma16(a, ld8(Wz + kk * 32), aiz);
                    ain = mfma16(a, ld8(Wn + kk * 32), ain);
                    ahr = mfma16(h, ld8(Ur + kk * 32), ahr);
                    ahz = mfma16(h, ld8(Uz + kk * 32), ahz);
                    ahn = mfma16(h, ld8(Un + kk * 32), ahn);
                }
            }
            #pragma unroll
            for (int r = 0; r < 4; ++r) {
                const int b = b0 + ko * 4 + r;
                const float rr = sigmf(air[r] + bir + ahr[r] + bhr);
                const float zz = sigmf(aiz[r] + biz + ahz[r] + bhz);
                const float nn = tanhf(ain[r] + bin + rr * (ahn[r] + bhn));
                const float hold = hi[b * 512 + n];
                const float hnew = (1.f - zz) * nn + zz * hold;
                ho[b * 512 + n] = hnew;
                hob[b * 512 + n] = f2b(hnew);
                if (t == 0) enc0[b * 512 + n] = hnew;
            }
            ec += 32; spinbar2(ebar, ec);
        }
    }
    gc += 256; spinbar(gbar, gc);   // encoder done; idle blocks waited here

    // ================= decoder: 100 steps, 3 barriers each =================
    #pragma unroll 1
    for (int td = 0; td < 100; ++td) {
        const float* hi  = h_f32 + (td & 1) * 32768;
        const short* hib = h_bf  + (td & 1) * 32768;
        float* ho  = h_f32 + ((td + 1) & 1) * 32768;
        short* hob = h_bf  + ((td + 1) & 1) * 32768;

        // ---- phase 1: attn+combine (blocks 0-63) || lossred(td-1) (64-127)
        if (bid < 64) {
            const int b = bid;
            const int tok = (td == 0) ? 1 : target_t[(td - 1) * 64 + b];
            for (int k = tid; k < 512; k += 256) {
                sx[k] = emb[(long long)tok * 512 + k];
                sx[512 + k] = hi[b * 512 + k];
            }
            __syncthreads();
            for (int nn = tid; nn < 400; nn += 256) {
                const fv4* wrow = (const fv4*)(attnW + (long long)nn * 1024);
                float acc = 0.f;
                for (int kc = 0; kc < 256; ++kc) {
                    fv4 v = wrow[kc];
                    acc += v[0] * sx[kc * 4 + 0] + v[1] * sx[kc * 4 + 1]
                         + v[2] * sx[kc * 4 + 2] + v[3] * sx[kc * 4 + 3];
                }
                sc[nn] = acc + attnb[nn];
            }
            __syncthreads();
            float m = -1e30f;
            for (int nn = tid; nn < 400; nn += 256) m = fmaxf(m, sc[nn]);
            red[tid] = m;
            __syncthreads();
            for (int s = 128; s > 0; s >>= 1) {
                if (tid < s) red[tid] = fmaxf(red[tid], red[tid + s]);
                __syncthreads();
            }
            m = red[0];
            __syncthreads();
            float ss = 0.f;
            for (int nn = tid; nn < 400; nn += 256) ss += expf(sc[nn] - m);
            red[tid] = ss;
            __syncthreads();
            for (int s = 128; s > 0; s >>= 1) {
                if (tid < s) red[tid] += red[tid + s];
                __syncthreads();
            }
            if (tid == 0) a0s = expf(sc[0] - m) / red[0];
            __syncthreads();
            const float a0b = a0s;
            for (int k = tid; k < 512; k += 256)
                sx[512 + k] = enc0[b * 512 + k] * a0b;
            __syncthreads();
            for (int j = tid; j < 512; j += 256) {
                const fv4* wrow = (const fv4*)(combW + (long long)j * 1024);
                float acc = 0.f;
                for (int kc = 0; kc < 256; ++kc) {
                    fv4 v = wrow[kc];
                    acc += v[0] * sx[kc * 4 + 0] + v[1] * sx[kc * 4 + 1]
                         + v[2] * sx[kc * 4 + 2] + v[3] * sx[kc * 4 + 3];
                }
                acc += combb[j];
                c_bf[b * 512 + j] = f2b(fmaxf(acc, 0.f));
            }
        } else if (bid < 128 && td > 0) {
            const int b = bid - 64;
            red[tid] = pm[tid * 64 + b]; rs2[tid] = ps[tid * 64 + b];
            __syncthreads();
            for (int st = 128; st > 0; st >>= 1) {
                if (tid < st) {
                    const float m2 = red[tid + st], s2 = rs2[tid + st];
                    const float M = fmaxf(red[tid], m2);
                    rs2[tid] = rs2[tid] * expf(red[tid] - M) + s2 * expf(m2 - M);
                    red[tid] = M;
                }
                __syncthreads();
            }
            if (tid == 0) {
                const float logp = tlog[b] - (red[0] + logf(rs2[0]));
                atomicAdd(lacc, -logp * (1.f / 64.f));
            }
        }
        gc += 256; spinbar(gbar, gc);

        // ---- phase 2: decoder GRU (blocks 0-31) ----
        if (bid < 32) {
            const int lane = tid & 63;
            const int w = bid * 4 + (tid >> 6);
            const int b0 = (w & 3) * 16, n0 = (w >> 2) * 16;
            const int l15 = lane & 15, ko = lane >> 4, koff = ko * 8;
            const int brow = b0 + l15, n = n0 + l15;
            const bh8* Ap = (const bh8*)(c_bf + (long long)brow * 512) + ko;
            const bh8* Hp = (const bh8*)(hib + (long long)brow * 512) + ko;
            fv4 air = {0.f, 0.f, 0.f, 0.f};
            fv4 aiz = air, ain = air, ahr = air, ahz = air, ahn = air;
            if (tier >= 1) {
                const bh8* Wr = (const bh8*)(decWb + (long long)(n + 0)    * 512) + ko;
                const bh8* Wz = (const bh8*)(decWb + (long long)(n + 512)  * 512) + ko;
                const bh8* Wn = (const bh8*)(decWb + (long long)(n + 1024) * 512) + ko;
                const bh8* Ur = (const bh8*)(decWb + (long long)(n + 1536) * 512) + ko;
                const bh8* Uz = (const bh8*)(decWb + (long long)(n + 2048) * 512) + ko;
                const bh8* Un = (const bh8*)(decWb + (long long)(n + 2560) * 512) + ko;
                #pragma unroll 4
                for (int kk = 0; kk < 16; ++kk) {
                    const bh8 a = Ap[kk * 4];
                    const bh8 h = Hp[kk * 4];
                    air = mfma16(a, Wr[kk * 4], air);
                    aiz = mfma16(a, Wz[kk * 4], aiz);
                    ain = mfma16(a, Wn[kk * 4], ain);
                    ahr = mfma16(h, Ur[kk * 4], ahr);
                    ahz = mfma16(h, Uz[kk * 4], ahz);
                    ahn = mfma16(h, Un[kk * 4], ahn);
                }
            } else {
                const float* Wr = decWih + (long long)(n + 0)    * 512 + koff;
                const float* Wz = decWih + (long long)(n + 512)  * 512 + koff;
                const float* Wn = decWih + (long long)(n + 1024) * 512 + koff;
                const float* Ur = decWhh + (long long)(n + 0)    * 512 + koff;
                const float* Uz = decWhh + (long long)(n + 512)  * 512 + koff;
                const float* Un = decWhh + (long long)(n + 1024) * 512 + koff;
                #pragma unroll 4
                for (int kk = 0; kk < 16; ++kk) {
                    const bh8 a = Ap[kk * 4];
                    const bh8 h = Hp[kk * 4];
                    air = mfma16(a, ld8(Wr + kk * 32), air);
                    aiz = mfma16(a, ld8(Wz + kk * 32), aiz);
                    ain = mfma16(a, ld8(Wn + kk * 32), ain);
                    ahr = mfma16(h, ld8(Ur + kk * 32), ahr);
                    ahz = mfma16(h, ld8(Uz + kk * 32), ahz);
                    ahn = mfma16(h, ld8(Un + kk * 32), ahn);
                }
            }
            const float bir = decbih[n], biz = decbih[n + 512], bin = decbih[n + 1024];
            const float bhr = decbhh[n], bhz = decbhh[n + 512], bhn = decbhh[n + 1024];
            #pragma unroll
            for (int r = 0; r < 4; ++r) {
                const int b = b0 + ko * 4 + r;
                const float rr = sigmf(air[r] + bir + ahr[r] + bhr);
                const float zz = sigmf(aiz[r] + biz + ahz[r] + bhz);
                const float nn = tanhf(ain[r] + bin + rr * (ahn[r] + bhn));
                const float hold = hi[b * 512 + n];
                const float hnew = (1.f - zz) * nn + zz * hold;
                ho[b * 512 + n] = hnew;
                hob[b * 512 + n] = f2b(hnew);
            }
        }
        gc += 256; spinbar(gbar, gc);

        // ---- phase 3: out-GEMM + logsumexp partials (all 256 blocks) ----
        {
            const int wl = tid >> 6, lane = tid & 63;
            const int l15 = lane & 15, ko = lane >> 4;
            const bh8* A0 = (const bh8*)(hob + (long long)(0  + l15) * 512) + ko;
            const bh8* A1 = (const bh8*)(hob + (long long)(16 + l15) * 512) + ko;
            const bh8* A2 = (const bh8*)(hob + (long long)(32 + l15) * 512) + ko;
            const bh8* A3 = (const bh8*)(hob + (long long)(48 + l15) * 512) + ko;
            const int row = tid & 63, q = tid >> 6;
            const int tg = target_t[td * 64 + row];
            float qm = -1e30f, qs = 0.f;
            #pragma unroll 1
            for (int j = 0; j < 4; ++j) {
                const int strip = bid * 4 + wl + 1024 * j;
                const int v = strip * 16 + l15;
                const int vcl = (v < 50000) ? v : 49999;
                fv4 c0 = {0.f, 0.f, 0.f, 0.f};
                fv4 c1 = c0, c2 = c0, c3 = c0;
                if (tier >= 2) {
                    const bh8* Bp = (const bh8*)(outWb + (long long)vcl * 512) + ko;
                    #pragma unroll 4
                    for (int kk = 0; kk < 16; ++kk) {
                        const bh8 bb = Bp[kk * 4];
                        c0 = mfma16(A0[kk * 4], bb, c0);
                        c1 = mfma16(A1[kk * 4], bb, c1);
                        c2 = mfma16(A2[kk * 4], bb, c2);
                        c3 = mfma16(A3[kk * 4], bb, c3);
                    }
                } else {
                    const float* Bp = outW + (long long)vcl * 512 + ko * 8;
                    #pragma unroll 4
                    for (int kk = 0; kk < 16; ++kk) {
                        const bh8 bb = ld8(Bp + kk * 32);
                        c0 = mfma16(A0[kk * 4], bb, c0);
                        c1 = mfma16(A1[kk * 4], bb, c1);
                        c2 = mfma16(A2[kk * 4], bb, c2);
                        c3 = mfma16(A3[kk * 4], bb, c3);
                    }
                }
                const float bv = outb[vcl];
                const bool ok = (v < 50000);
                const int cc = wl * 16 + l15;
                #pragma unroll
                for (int r = 0; r < 4; ++r) {
                    const int rw = ko * 4 + r;
                    sl[0  + rw][cc] = ok ? (c0[r] + bv) : -1e30f;
                    sl[16 + rw][cc] = ok ? (c1[r] + bv) : -1e30f;
                    sl[32 + rw][cc] = ok ? (c2[r] + bv) : -1e30f;
                    sl[48 + rw][cc] = ok ? (c3[r] + bv) : -1e30f;
                }
                __syncthreads();
                const int vb = (bid * 4 + q + 1024 * j) * 16;
                for (int i = 0; i < 16; ++i) {
                    const float x = sl[row][q * 16 + i];
                    if (x > qm) { qs = qs * expf(qm - x) + 1.f; qm = x; }
                    else        { qs += expf(x - qm); }
                }
                const int rel = tg - vb;
                if (rel >= 0 && rel < 16) tlog[row] = sl[row][q * 16 + rel];
                __syncthreads();
            }
            sqm[tid] = qm; sqs[tid] = qs;   // tid = q*64 + row
            __syncthreads();
            if (tid < 64) {
                float m = -1e30f, s = 0.f;
                for (int q2 = 0; q2 < 4; ++q2) {
                    const float m2 = sqm[q2 * 64 + tid], s2 = sqs[q2 * 64 + tid];
                    if (m2 > m) { s = s * expf(m - m2) + s2; m = m2; }
                    else        { s += s2 * expf(m2 - m); }
                }
                pm[bid * 64 + tid] = m; ps[bid * 64 + tid] = s;
            }
        }
        gc += 256; spinbar(gbar, gc);
    }

    // ---- final lossred for td=99 ----
    if (bid >= 64 && bid < 128) {
        const int b = bid - 64;
        red[tid] = pm[tid * 64 + b]; rs2[tid] = ps[tid * 64 + b];
        __syncthreads();
        for (int st = 128; st > 0; st >>= 1) {
            if (tid < st) {
                const float m2 = red[tid + st], s2 = rs2[tid + st];
                const float M = fmaxf(red[tid], m2);
                rs2[tid] = rs2[tid] * expf(red[tid] - M) + s2 * expf(m2 - M);
                red[tid] = M;
            }
            __syncthreads();
        }
        if (tid == 0) {
            const float logp = tlog[b] - (red[0] + logf(rs2[0]));
            atomicAdd(lacc, -logp * (1.f / 64.f));
        }
    }
    gc += 256; spinbar(gbar, gc);
    if (bid == 0 && tid == 0) outp[0] = *lacc;
}

extern "C" void kernel_launch(void* const* d_in, const int* in_sizes, int n_in,
                              void* d_out, int out_size, void* d_ws, size_t ws_size,
                              hipStream_t stream)
{
    const float* emb     = (const float*)d_in[0];
    const float* enc_Wih = (const float*)d_in[1];
    const float* enc_Whh = (const float*)d_in[2];
    const float* enc_bih = (const float*)d_in[3];
    const float* enc_bhh = (const float*)d_in[4];
    const float* attn_W  = (const float*)d_in[5];
    const float* attn_b  = (const float*)d_in[6];
    const float* comb_W  = (const float*)d_in[7];
    const float* comb_b  = (const float*)d_in[8];
    const float* dec_Wih = (const float*)d_in[9];
    const float* dec_Whh = (const float*)d_in[10];
    const float* dec_bih = (const float*)d_in[11];
    const float* dec_bhh = (const float*)d_in[12];
    const float* out_W   = (const float*)d_in[13];
    const float* out_b   = (const float*)d_in[14];
    const int*   input_t = (const int*)d_in[15];
    const int*   target_t= (const int*)d_in[16];

    char* ws = (char*)d_ws;
    float* h_f32 = (float*)(ws + 0);          // 2 x [64,512] f32
    float* enc0  = (float*)(ws + 262144);     // [64,512] f32
    short* h_bf  = (short*)(ws + 393216);     // 2 x [64,512] bf16
    short* c_bf  = (short*)(ws + 524288);     // [64,512] bf16
    float* lacc  = (float*)(ws + 589824);
    unsigned int* gbar = (unsigned int*)(ws + 593920);
    unsigned int* ebar = (unsigned int*)(ws + 598016);
    float* tlog  = (float*)(ws + 602112);     // [64]
    float* pm    = (float*)(ws + 602368);     // [256,64] f32
    float* ps    = (float*)(ws + 667904);     // [256,64] f32
    short* encWb = (short*)(ws + 733440);     // [3072,512] bf16
    short* decWb = (short*)(ws + 3879168);    // [3072,512] bf16
    short* outWb = (short*)(ws + 7024896);    // [50000,512] bf16

    int tier = 0;
    if (ws_size >= 7024896)  tier = 1;
    if (ws_size >= 58224896) tier = 2;

    k_init<<<1, 1, 0, stream>>>(lacc, gbar, ebar);
    k_mega<<<256, 256, 0, stream>>>(
        emb, enc_Wih, enc_Whh, enc_bih, enc_bhh,
        attn_W, attn_b, comb_W, comb_b,
        dec_Wih, dec_Whh, dec_bih, dec_bhh,
        out_W, out_b, input_t, target_t,
        h_f32, h_bf, enc0, c_bf, pm, ps, tlog, lacc,
        gbar, ebar, encWb, decWb, outWb, tier, (float*)d_out);
}